// Round 4
// baseline (8907.333 us; speedup 1.0000x reference)
//
#include <hip/hip_runtime.h>
#include <hip/hip_bf16.h>

typedef __bf16 bf16_8 __attribute__((ext_vector_type(8)));
typedef float floatx4 __attribute__((ext_vector_type(4)));

#define TT 2048
#define HH 1024
#define CC 128
#define LSTEPS 16

__device__ __forceinline__ size_t mapped_off(int r, int kstep) {
    // row r of [chunk,batch] grid -> (b = r&63, c = r>>6), t = c*LSTEPS + kstep
    return ((size_t)(r & 63) * TT + (size_t)(r >> 6) * LSTEPS + (size_t)kstep) * HH;
}

__device__ __forceinline__ void gload16(const void* g, void* l) {
    __builtin_amdgcn_global_load_lds(
        (const __attribute__((address_space(1))) unsigned int*)g,
        (__attribute__((address_space(3))) unsigned int*)l,
        16, 0, 0);
}

// ---------------------------------------------------------------------------
// step_gemm: C[M][1024] = A[M][K] * B[N][K]^T (split-3 bf16).
// 64x128 tile, BK=64, 512 threads (8 waves 2x4, wave tile 32x32).
// 48 KB LDS -> 3 blocks/CU (round-2 verified: 68% occupancy; round-3 showed
// 128KB dbuf kills occupancy -> regression; do NOT grow LDS).
// XCD-swizzled blockIdx: requires gridDim.x*gridDim.y % 8 == 0. Each XCD gets
// a contiguous row-major chunk of tiles -> A-panels and U stay in its L2
// (round-3 evidence: FETCH 526->70 MB on wx).
// bias_mode: 0 none, 1 per-col vector, 2 direct [r*HH+n], 3 mapped (b,t).
// outf_mode: 2 direct, 3 mapped. outhi/outlo: direct [M][HH] (optional).
// ---------------------------------------------------------------------------
__global__ __launch_bounds__(512) void step_gemm(
    const __bf16* Ahi, const __bf16* Alo,
    const __bf16* Bhi, const __bf16* Blo,
    int M, int K,
    const float* bias, int bias_mode, int kstep,
    float* outf, int outf_mode,
    __bf16* outhi, __bf16* outlo)
{
    __shared__ __align__(16) __bf16 As_hi[64][64];    // 8 KB
    __shared__ __align__(16) __bf16 As_lo[64][64];    // 8 KB
    __shared__ __align__(16) __bf16 Bs_hi[128][64];   // 16 KB
    __shared__ __align__(16) __bf16 Bs_lo[128][64];   // 16 KB

    const int tid  = threadIdx.x;
    const int lane = tid & 63;
    const int wid  = tid >> 6;          // 0..7
    const int wr   = wid >> 2;          // 0..1 over M (32 rows each)
    const int wc   = wid & 3;           // 0..3 over N (32 cols each)

    // bijective XCD swizzle (nwg % 8 == 0): XCD k gets tiles [k*nwg/8, ...)
    const int nx     = gridDim.x;
    const int nwg    = nx * gridDim.y;
    const int linear = blockIdx.y * nx + blockIdx.x;
    const int swz    = (linear & 7) * (nwg >> 3) + (linear >> 3);
    const int m0     = (swz / nx) * 64;
    const int n0     = (swz % nx) * 128;

    const bool has_a   = (Ahi != nullptr);
    const bool has_alo = (Alo != nullptr);
    const bool has_blo = (Blo != nullptr);

    floatx4 acc[2][2];
#pragma unroll
    for (int i = 0; i < 2; ++i)
#pragma unroll
        for (int j = 0; j < 2; ++j) {
            floatx4 z = {0.0f, 0.0f, 0.0f, 0.0f};
            acc[i][j] = z;
        }

    // staging geometry: one gload16 call covers 512 lanes x 16B = 8KB.
    // LDS linear offset = wid*1024 + lane*16  ->  row = tid>>3, col = (tid&7)*8
    const int srow = tid >> 3;
    const int scol = (tid & 7) << 3;
    __bf16* AhiW  = &As_hi[0][0] + wid * 512;          // wave-uniform bases
    __bf16* AloW  = &As_lo[0][0] + wid * 512;
    __bf16* BhiW0 = &Bs_hi[0][0] + wid * 512;
    __bf16* BhiW1 = &Bs_hi[0][0] + 4096 + wid * 512;
    __bf16* BloW0 = &Bs_lo[0][0] + wid * 512;
    __bf16* BloW1 = &Bs_lo[0][0] + 4096 + wid * 512;

    const int lm = lane & 15;

    if (has_a) {
        const size_t a_off  = (size_t)(m0 + srow) * K + scol;
        const size_t b_off0 = (size_t)(n0 + srow) * K + scol;
        const size_t b_off1 = (size_t)(n0 + 64 + srow) * K + scol;

        for (int kt = 0; kt < K; kt += 64) {
            // ---- stage tiles via global_load_lds (width 16) ----
            gload16(Ahi + a_off + kt, AhiW);
            if (has_alo) gload16(Alo + a_off + kt, AloW);
            gload16(Bhi + b_off0 + kt, BhiW0);
            gload16(Bhi + b_off1 + kt, BhiW1);
            if (has_blo) {
                gload16(Blo + b_off0 + kt, BloW0);
                gload16(Blo + b_off1 + kt, BloW1);
            }
            __syncthreads();

            // ---- compute ----
#pragma unroll
            for (int ks = 0; ks < 64; ks += 32) {
                const int kk = ks + ((lane >> 4) << 3);
                bf16_8 ah[2], al[2], bh[2], bl[2];
#pragma unroll
                for (int i = 0; i < 2; ++i) {
                    ah[i] = *(const bf16_8*)&As_hi[wr * 32 + i * 16 + lm][kk];
                    if (has_alo) al[i] = *(const bf16_8*)&As_lo[wr * 32 + i * 16 + lm][kk];
                }
#pragma unroll
                for (int j = 0; j < 2; ++j) {
                    bh[j] = *(const bf16_8*)&Bs_hi[wc * 32 + j * 16 + lm][kk];
                    if (has_blo) bl[j] = *(const bf16_8*)&Bs_lo[wc * 32 + j * 16 + lm][kk];
                }
#pragma unroll
                for (int i = 0; i < 2; ++i)
#pragma unroll
                    for (int j = 0; j < 2; ++j) {
                        acc[i][j] = __builtin_amdgcn_mfma_f32_16x16x32_bf16(ah[i], bh[j], acc[i][j], 0, 0, 0);
                        if (has_alo)
                            acc[i][j] = __builtin_amdgcn_mfma_f32_16x16x32_bf16(al[i], bh[j], acc[i][j], 0, 0, 0);
                        if (has_blo)
                            acc[i][j] = __builtin_amdgcn_mfma_f32_16x16x32_bf16(ah[i], bl[j], acc[i][j], 0, 0, 0);
                    }
            }
            __syncthreads();
        }
    }

    // ---- epilogue ----
    const int lq = lane >> 4;
#pragma unroll
    for (int i = 0; i < 2; ++i) {
#pragma unroll
        for (int j = 0; j < 2; ++j) {
            const int gc = n0 + wc * 32 + j * 16 + lm;
#pragma unroll
            for (int rr = 0; rr < 4; ++rr) {
                const int gr = m0 + wr * 32 + i * 16 + lq * 4 + rr;
                if (gr < M) {
                    float v = acc[i][j][rr];
                    if (bias_mode == 1)      v += bias[gc];
                    else if (bias_mode == 2) v += bias[(size_t)gr * HH + gc];
                    else if (bias_mode == 3) v += bias[mapped_off(gr, kstep) + gc];
                    if (outf) {
                        size_t o = (outf_mode == 3 ? mapped_off(gr, kstep)
                                                   : (size_t)gr * HH) + gc;
                        outf[o] = v;
                    }
                    if (outhi) {
                        size_t o = (size_t)gr * HH + gc;
                        __bf16 h = (__bf16)v;
                        outhi[o] = h;
                        outlo[o] = (__bf16)(v - (float)h);
                    }
                }
            }
        }
    }
}

// ---------------------------------------------------------------------------
// Old generic kernel: kept for the U-power squarings (k-major B staging).
// ---------------------------------------------------------------------------
__global__ __launch_bounds__(256) void gemm_step(
    const void* Ahi_, const __bf16* Alo, int a_f32,
    const __bf16* Bthi, const __bf16* Btlo, int b_kmajor,
    int M, int K,
    const float* bias, int bias_mode, int kstep,
    float* outf, int outf_mode,
    __bf16* outhi, __bf16* outlo)
{
    __shared__ __align__(16) __bf16 As_hi[128][72];
    __shared__ __align__(16) __bf16 As_lo[128][72];
    __shared__ __align__(16) __bf16 Bs_hi[128][72];
    __shared__ __align__(16) __bf16 Bs_lo[128][72];

    const int tid  = threadIdx.x;
    const int lane = tid & 63;
    const int wid  = tid >> 6;
    const int wr = wid >> 1, wc = wid & 1;
    const int m0 = blockIdx.y * 128;
    const int n0 = blockIdx.x * 128;
    const bool has_a   = (Ahi_ != nullptr);
    const bool has_alo = (Alo  != nullptr);
    const bool has_blo = (Btlo != nullptr);

    floatx4 acc[4][4];
#pragma unroll
    for (int i = 0; i < 4; ++i)
#pragma unroll
        for (int j = 0; j < 4; ++j) {
            floatx4 z = {0.0f, 0.0f, 0.0f, 0.0f};
            acc[i][j] = z;
        }

    if (has_a) {
        const __bf16* Ahi = (const __bf16*)Ahi_;
        const float*  Af  = (const float*)Ahi_;
        for (int kt = 0; kt < K; kt += 64) {
#pragma unroll
            for (int it = 0; it < 4; ++it) {
                int chunk = tid + it * 256;
                int row = chunk >> 3;
                int col = (chunk & 7) << 3;
                if (a_f32) {
                    const float* src = Af + (size_t)(m0 + row) * K + kt + col;
                    float4 f0 = *(const float4*)src;
                    float4 f1 = *(const float4*)(src + 4);
                    __bf16* d = &As_hi[row][col];
                    d[0]=(__bf16)f0.x; d[1]=(__bf16)f0.y; d[2]=(__bf16)f0.z; d[3]=(__bf16)f0.w;
                    d[4]=(__bf16)f1.x; d[5]=(__bf16)f1.y; d[6]=(__bf16)f1.z; d[7]=(__bf16)f1.w;
                } else {
                    *(bf16_8*)&As_hi[row][col] =
                        *(const bf16_8*)(Ahi + (size_t)(m0 + row) * K + kt + col);
                    if (has_alo)
                        *(bf16_8*)&As_lo[row][col] =
                            *(const bf16_8*)(Alo + (size_t)(m0 + row) * K + kt + col);
                }
            }
            if (!b_kmajor) {
#pragma unroll
                for (int it = 0; it < 4; ++it) {
                    int chunk = tid + it * 256;
                    int row = chunk >> 3;
                    int col = (chunk & 7) << 3;
                    *(bf16_8*)&Bs_hi[row][col] =
                        *(const bf16_8*)(Bthi + (size_t)(n0 + row) * K + kt + col);
                    if (has_blo)
                        *(bf16_8*)&Bs_lo[row][col] =
                            *(const bf16_8*)(Btlo + (size_t)(n0 + row) * K + kt + col);
                }
            } else {
#pragma unroll
                for (int it = 0; it < 4; ++it) {
                    int chunk = tid + it * 256;
                    int krow = chunk >> 4;
                    int ncol = (chunk & 15) << 3;
                    bf16_8 v = *(const bf16_8*)(Bthi + (size_t)(kt + krow) * HH + n0 + ncol);
#pragma unroll
                    for (int e = 0; e < 8; ++e) Bs_hi[ncol + e][krow] = v[e];
                    if (has_blo) {
                        bf16_8 w = *(const bf16_8*)(Btlo + (size_t)(kt + krow) * HH + n0 + ncol);
#pragma unroll
                        for (int e = 0; e < 8; ++e) Bs_lo[ncol + e][krow] = w[e];
                    }
                }
            }
            __syncthreads();
#pragma unroll
            for (int ks = 0; ks < 64; ks += 32) {
                const int lm = lane & 15;
                const int kk = ks + (lane >> 4) * 8;
                bf16_8 ah[4], al[4], bh[4], bl[4];
#pragma unroll
                for (int i = 0; i < 4; ++i) {
                    ah[i] = *(const bf16_8*)&As_hi[wr * 64 + i * 16 + lm][kk];
                    if (has_alo) al[i] = *(const bf16_8*)&As_lo[wr * 64 + i * 16 + lm][kk];
                }
#pragma unroll
                for (int j = 0; j < 4; ++j) {
                    bh[j] = *(const bf16_8*)&Bs_hi[wc * 64 + j * 16 + lm][kk];
                    if (has_blo) bl[j] = *(const bf16_8*)&Bs_lo[wc * 64 + j * 16 + lm][kk];
                }
#pragma unroll
                for (int i = 0; i < 4; ++i)
#pragma unroll
                    for (int j = 0; j < 4; ++j) {
                        acc[i][j] = __builtin_amdgcn_mfma_f32_16x16x32_bf16(ah[i], bh[j], acc[i][j], 0, 0, 0);
                        if (has_alo)
                            acc[i][j] = __builtin_amdgcn_mfma_f32_16x16x32_bf16(al[i], bh[j], acc[i][j], 0, 0, 0);
                        if (has_blo)
                            acc[i][j] = __builtin_amdgcn_mfma_f32_16x16x32_bf16(ah[i], bl[j], acc[i][j], 0, 0, 0);
                    }
            }
            __syncthreads();
        }
    }

    const int lm = lane & 15, lq = lane >> 4;
#pragma unroll
    for (int i = 0; i < 4; ++i) {
#pragma unroll
        for (int j = 0; j < 4; ++j) {
            int gc = n0 + wc * 64 + j * 16 + lm;
#pragma unroll
            for (int rr = 0; rr < 4; ++rr) {
                int gr = m0 + wr * 64 + i * 16 + lq * 4 + rr;
                if (gr < M) {
                    float v = acc[i][j][rr];
                    if (bias_mode == 1)      v += bias[gc];
                    else if (bias_mode == 2) v += bias[(size_t)gr * HH + gc];
                    else if (bias_mode == 3) v += bias[mapped_off(gr, kstep) + gc];
                    if (outf) {
                        size_t o = (outf_mode == 3 ? mapped_off(gr, kstep)
                                                   : (size_t)gr * HH) + gc;
                        outf[o] = v;
                    }
                    if (outhi) {
                        size_t o = (size_t)gr * HH + gc;
                        __bf16 h = (__bf16)v;
                        outhi[o] = h;
                        outlo[o] = (__bf16)(v - (float)h);
                    }
                }
            }
        }
    }
}

__global__ void split_kernel(const float* src, __bf16* hi, __bf16* lo, int n) {
    int i = blockIdx.x * 256 + threadIdx.x;
    if (i < n) {
        float v = src[i];
        __bf16 h = (__bf16)v;
        hi[i] = h;
        lo[i] = (__bf16)(v - (float)h);
    }
}

__global__ void prep_wb(const float* W, const float* Ub, const float* bvec,
                        __bf16* Whi, float* biasv) {
    int i = blockIdx.x * 256 + threadIdx.x;
    if (i < 512 * 1024) {
        Whi[i] = (__bf16)W[i];
    } else if (i < 512 * 1024 + 1024) {
        int n = i - 512 * 1024;
        biasv[n] = Ub[n] + bvec[n];
    }
}

// Vectorized fp32 -> bf16 cast for x (8 elems/thread, exact grid coverage).
__global__ void cast_hi_kernel(const float* src, __bf16* hi) {
    size_t i = (size_t)blockIdx.x * 256 + threadIdx.x;
    float4 a = *(const float4*)(src + i * 8);
    float4 b = *(const float4*)(src + i * 8 + 4);
    bf16_8 v;
    v[0] = (__bf16)a.x; v[1] = (__bf16)a.y; v[2] = (__bf16)a.z; v[3] = (__bf16)a.w;
    v[4] = (__bf16)b.x; v[5] = (__bf16)b.y; v[6] = (__bf16)b.z; v[7] = (__bf16)b.w;
    *(bf16_8*)(hi + i * 8) = v;
}

// Build phase-3 initial state: rows of chunk c get e_{c-1} (chunk 0 gets zeros).
// i over CC*64*1024 elements.
__global__ void p3init_kernel(const __bf16* Hhi, const __bf16* Hlo,
                              __bf16* S0hi, __bf16* S0lo) {
    size_t i = (size_t)blockIdx.x * 256 + threadIdx.x;
    int col = (int)(i & 1023);
    int r = (int)(i >> 10);
    int c = r >> 6;
    int b = r & 63;
    if (c == 0) {
        S0hi[i] = (__bf16)0.0f;
        S0lo[i] = (__bf16)0.0f;
    } else {
        size_t src = ((size_t)((c - 1) * 64 + b) << 10) + col;
        S0hi[i] = Hhi[src];
        S0lo[i] = Hlo[src];
    }
}

extern "C" void kernel_launch(void* const* d_in, const int* in_sizes, int n_in,
                              void* d_out_, int out_size, void* d_ws, size_t ws_size,
                              hipStream_t stream) {
    const float* x   = (const float*)d_in[0];  // [64,2048,512]
    const float* W   = (const float*)d_in[1];  // [1024,512]
    const float* Uw  = (const float*)d_in[2];  // [1024,1024]
    const float* Ub  = (const float*)d_in[3];  // [1024]
    const float* bvec= (const float*)d_in[4];  // [1024] (zeros)
    float* out = (float*)d_out_;               // [64,2048,1024]

    const int MROWS = CC * 64;                 // 8192 scan rows

    char* p = (char*)d_ws;
    size_t need = 0;
    auto alloc = [&](size_t bytes) { char* r = p; p += bytes; need += bytes; return r; };
    __bf16* Uhi  = (__bf16*)alloc(2097152);
    __bf16* Ulo  = (__bf16*)alloc(2097152);
    __bf16* Whi  = (__bf16*)alloc(1048576);
    float*  biasv= (float*) alloc(4096);
    __bf16* Phi  = (__bf16*)alloc(2097152);
    __bf16* Plo  = (__bf16*)alloc(2097152);
    __bf16* Qhi  = (__bf16*)alloc(2097152);
    __bf16* Qlo  = (__bf16*)alloc(2097152);
    __bf16* SAhi = (__bf16*)alloc(16777216);   // [8192][1024] bf16
    __bf16* SAlo = (__bf16*)alloc(16777216);
    __bf16* SBhi = (__bf16*)alloc(16777216);
    __bf16* SBlo = (__bf16*)alloc(16777216);
    float*  Sf   = (float*) alloc(33554432);   // [128][64][1024] fp32
    __bf16* Hhi  = (__bf16*)alloc(16777216);   // [128][64][1024] bf16
    __bf16* Hlo  = (__bf16*)alloc(16777216);
    size_t base_need = need;
    __bf16* xhi  = (__bf16*)alloc(134217728);  // optional bf16 copy of x
    const bool use_xhi = (ws_size >= need);
    if (ws_size < base_need) return;  // workspace too small: fail loudly

    // prep: split Uw, quantize W, bias vector
    split_kernel<<<4096, 256, 0, stream>>>(Uw, Uhi, Ulo, 1024 * 1024);
    prep_wb<<<2052, 256, 0, stream>>>(W, Ub, bvec, Whi, biasv);

    // wx = x*W^T + Ub + b -> d_out (fp32), M=131072 rows == (b,t) layout
    if (use_xhi) {
        cast_hi_kernel<<<32768, 256, 0, stream>>>(x, xhi);
        step_gemm<<<dim3(8, 2048), 512, 0, stream>>>(
            xhi, nullptr, Whi, nullptr, 131072, 512,
            biasv, 1, 0, out, 2, nullptr, nullptr);
    } else {
        gemm_step<<<dim3(8, 1024), 256, 0, stream>>>(
            (const void*)x, nullptr, 1, Whi, nullptr, 0,
            131072, 512, biasv, 1, 0, out, 2, nullptr, nullptr);
    }

    // U^16 by repeated squaring (split-3, k-major B = same matrix)
    gemm_step<<<dim3(8, 8), 256, 0, stream>>>((const void*)Uhi, Ulo, 0, Uhi, Ulo, 1,
        1024, 1024, nullptr, 0, 0, nullptr, 0, Qhi, Qlo);              // U^2
    gemm_step<<<dim3(8, 8), 256, 0, stream>>>((const void*)Qhi, Qlo, 0, Qhi, Qlo, 1,
        1024, 1024, nullptr, 0, 0, nullptr, 0, Phi, Plo);              // U^4
    gemm_step<<<dim3(8, 8), 256, 0, stream>>>((const void*)Phi, Plo, 0, Phi, Plo, 1,
        1024, 1024, nullptr, 0, 0, nullptr, 0, Qhi, Qlo);              // U^8
    gemm_step<<<dim3(8, 8), 256, 0, stream>>>((const void*)Qhi, Qlo, 0, Qhi, Qlo, 1,
        1024, 1024, nullptr, 0, 0, nullptr, 0, Phi, Plo);              // U^16 -> P
    __bf16* Pwh = Phi;  // boundary propagator U^LSTEPS
    __bf16* Pwl = Plo;

    // phase 1: local scans (zero init), 128 chunks x 64 batch = 8192 rows.
    // Sf only needs the chunk-end value -> write it on the last step only.
    // hi/lo of the last step are dead (p3init overwrites) -> skip them.
    __bf16 *pin_hi = SAhi, *pin_lo = SAlo, *pout_hi = SBhi, *pout_lo = SBlo;
    for (int k = 0; k < LSTEPS; ++k) {
        const __bf16* ah = (k == 0) ? nullptr : pin_hi;
        const __bf16* al = (k == 0) ? nullptr : pin_lo;
        float* of = (k == LSTEPS - 1) ? Sf : nullptr;
        __bf16* oh = (k == LSTEPS - 1) ? nullptr : pout_hi;
        __bf16* ol = (k == LSTEPS - 1) ? nullptr : pout_lo;
        step_gemm<<<dim3(8, CC), 512, 0, stream>>>(
            ah, al, Uhi, Ulo, MROWS, 1024, out, 3, k, of, 2, oh, ol);
        __bf16* t;
        t = pin_hi; pin_hi = pout_hi; pout_hi = t;
        t = pin_lo; pin_lo = pout_lo; pout_lo = t;
    }

    // phase 2: chunk-boundary propagation e_c = U^16 e_{c-1} + local_end_c
    for (int c = 0; c < CC; ++c) {
        const __bf16* ah = (c == 0) ? nullptr : Hhi + (size_t)(c - 1) * 65536;
        const __bf16* al = (c == 0) ? nullptr : Hlo + (size_t)(c - 1) * 65536;
        step_gemm<<<dim3(8, 1), 512, 0, stream>>>(
            ah, al, Pwh, Pwl, 64, 1024,
            Sf + (size_t)c * 65536, 2, 0, nullptr, 0,
            Hhi + (size_t)c * 65536, Hlo + (size_t)c * 65536);
    }

    // phase-3 init: chunk c rows <- e_{c-1}
    p3init_kernel<<<CC * 256, 256, 0, stream>>>(Hhi, Hlo, SAhi, SAlo);

    // phase 3: rescan with true inits, writing d_out in place.
    // hi/lo of the last step are never read -> skip them.
    pin_hi = SAhi; pin_lo = SAlo; pout_hi = SBhi; pout_lo = SBlo;
    for (int k = 0; k < LSTEPS; ++k) {
        __bf16* oh = (k == LSTEPS - 1) ? nullptr : pout_hi;
        __bf16* ol = (k == LSTEPS - 1) ? nullptr : pout_lo;
        step_gemm<<<dim3(8, CC), 512, 0, stream>>>(
            pin_hi, pin_lo, Uhi, Ulo, MROWS, 1024, out, 3, k, out, 3, oh, ol);
        __bf16* t;
        t = pin_hi; pin_hi = pout_hi; pout_hi = t;
        t = pin_lo; pin_lo = pout_lo; pout_lo = t;
    }
}

// Round 5
// 5868.922 us; speedup vs baseline: 1.5177x; 1.5177x over previous
//
#include <hip/hip_runtime.h>
#include <hip/hip_bf16.h>

typedef __bf16 bf16_8 __attribute__((ext_vector_type(8)));
typedef float floatx4 __attribute__((ext_vector_type(4)));

#define TT 2048
#define HH 1024
#define CC 64
#define LSTEPS 32

__device__ __forceinline__ size_t mapped_off(int r, int kstep) {
    // row r of [chunk,batch] grid -> (b = r&63, c = r>>6), t = c*LSTEPS + kstep
    return ((size_t)(r & 63) * TT + (size_t)(r >> 6) * LSTEPS + (size_t)kstep) * HH;
}

__device__ __forceinline__ void gload16(const void* g, void* l) {
    __builtin_amdgcn_global_load_lds(
        (const __attribute__((address_space(1))) unsigned int*)g,
        (__attribute__((address_space(3))) unsigned int*)l,
        16, 0, 0);
}

// Swizzled LDS read: tile rows are 64 bf16 = 128 B = 8 slots of 16 B.
// Data for logical (row, slot) lives at (row, slot ^ (row&7)) -- the same
// involution is applied on the staging SOURCE address (rule #21: both sides).
// Breaks the 16-way bank conflict of the linear layout (128B stride => bank
// determined by slot only; 16 lanes/quarter-wave shared one slot).
__device__ __forceinline__ bf16_8 lds_read_swz(const __bf16* base, int row, int kk) {
    return *(const bf16_8*)(base + (size_t)row * 64 + (((kk >> 3) ^ (row & 7)) << 3));
}

// ---------------------------------------------------------------------------
// step_gemm: C[M][1024] = A[M][K] * B[N][K]^T (split-3 bf16).
// 64x128 tile, BK=64, 512 threads (8 waves 2x4, wave tile 32x32).
// 48 KB LDS -> 3 blocks/CU (round-3 showed 128KB dbuf kills occupancy).
// XCD-swizzled blockIdx (round-4: FETCH 526->76 MB, time-neutral, kept).
// LDS XOR-swizzle via pre-swizzled global source + swizzled read (this round:
// round-4 counters showed 1.0e8 bank-conflict cycles/dispatch = 16-way).
// bias_mode: 0 none, 1 per-col vector, 2 direct [r*HH+n], 3 mapped (b,t).
// outf_mode: 2 direct, 3 mapped. outhi/outlo: direct [M][HH] (optional).
// ---------------------------------------------------------------------------
__global__ __launch_bounds__(512) void step_gemm(
    const __bf16* Ahi, const __bf16* Alo,
    const __bf16* Bhi, const __bf16* Blo,
    int M, int K,
    const float* bias, int bias_mode, int kstep,
    float* outf, int outf_mode,
    __bf16* outhi, __bf16* outlo)
{
    __shared__ __align__(16) __bf16 As_hi[64][64];    // 8 KB
    __shared__ __align__(16) __bf16 As_lo[64][64];    // 8 KB
    __shared__ __align__(16) __bf16 Bs_hi[128][64];   // 16 KB
    __shared__ __align__(16) __bf16 Bs_lo[128][64];   // 16 KB

    const int tid  = threadIdx.x;
    const int lane = tid & 63;
    const int wid  = tid >> 6;          // 0..7
    const int wr   = wid >> 2;          // 0..1 over M (32 rows each)
    const int wc   = wid & 3;           // 0..3 over N (32 cols each)

    // bijective XCD swizzle (nwg % 8 == 0): XCD k gets a contiguous tile range
    const int nx     = gridDim.x;
    const int nwg    = nx * gridDim.y;
    const int linear = blockIdx.y * nx + blockIdx.x;
    const int swz    = (linear & 7) * (nwg >> 3) + (linear >> 3);
    const int m0     = (swz / nx) * 64;
    const int n0     = (swz % nx) * 128;

    const bool has_a   = (Ahi != nullptr);
    const bool has_alo = (Alo != nullptr);
    const bool has_blo = (Blo != nullptr);

    floatx4 acc[2][2];
#pragma unroll
    for (int i = 0; i < 2; ++i)
#pragma unroll
        for (int j = 0; j < 2; ++j) {
            floatx4 z = {0.0f, 0.0f, 0.0f, 0.0f};
            acc[i][j] = z;
        }

    // staging geometry: one gload16 call covers 512 lanes x 16B = 8KB (64 rows).
    // LDS dest is LINEAR: offset = tid*16B  (row = tid>>3, slot = tid&7).
    // SOURCE slot is XOR-swizzled so LDS (row, s) holds global (row, s^(row&7)).
    const int srow = tid >> 3;
    const int scol = (((tid & 7) ^ (srow & 7)) << 3);   // swizzled source slot
    __bf16* AhiW  = &As_hi[0][0] + wid * 512;           // wave-uniform bases
    __bf16* AloW  = &As_lo[0][0] + wid * 512;
    __bf16* BhiW0 = &Bs_hi[0][0] + wid * 512;
    __bf16* BhiW1 = &Bs_hi[0][0] + 4096 + wid * 512;
    __bf16* BloW0 = &Bs_lo[0][0] + wid * 512;
    __bf16* BloW1 = &Bs_lo[0][0] + 4096 + wid * 512;

    const int lm = lane & 15;

    if (has_a) {
        const size_t a_off  = (size_t)(m0 + srow) * K + scol;
        const size_t b_off0 = (size_t)(n0 + srow) * K + scol;
        const size_t b_off1 = (size_t)(n0 + 64 + srow) * K + scol;

        for (int kt = 0; kt < K; kt += 64) {
            // ---- stage tiles via global_load_lds (width 16) ----
            gload16(Ahi + a_off + kt, AhiW);
            if (has_alo) gload16(Alo + a_off + kt, AloW);
            gload16(Bhi + b_off0 + kt, BhiW0);
            gload16(Bhi + b_off1 + kt, BhiW1);
            if (has_blo) {
                gload16(Blo + b_off0 + kt, BloW0);
                gload16(Blo + b_off1 + kt, BloW1);
            }
            __syncthreads();

            // ---- compute ----
#pragma unroll
            for (int ks = 0; ks < 64; ks += 32) {
                const int kk = ks + ((lane >> 4) << 3);
                bf16_8 ah[2], al[2], bh[2], bl[2];
#pragma unroll
                for (int i = 0; i < 2; ++i) {
                    const int ar = wr * 32 + i * 16 + lm;
                    ah[i] = lds_read_swz(&As_hi[0][0], ar, kk);
                    if (has_alo) al[i] = lds_read_swz(&As_lo[0][0], ar, kk);
                }
#pragma unroll
                for (int j = 0; j < 2; ++j) {
                    const int br = wc * 32 + j * 16 + lm;
                    bh[j] = lds_read_swz(&Bs_hi[0][0], br, kk);
                    if (has_blo) bl[j] = lds_read_swz(&Bs_lo[0][0], br, kk);
                }
#pragma unroll
                for (int i = 0; i < 2; ++i)
#pragma unroll
                    for (int j = 0; j < 2; ++j) {
                        acc[i][j] = __builtin_amdgcn_mfma_f32_16x16x32_bf16(ah[i], bh[j], acc[i][j], 0, 0, 0);
                        if (has_alo)
                            acc[i][j] = __builtin_amdgcn_mfma_f32_16x16x32_bf16(al[i], bh[j], acc[i][j], 0, 0, 0);
                        if (has_blo)
                            acc[i][j] = __builtin_amdgcn_mfma_f32_16x16x32_bf16(ah[i], bl[j], acc[i][j], 0, 0, 0);
                    }
            }
            __syncthreads();
        }
    }

    // ---- epilogue (M is always a multiple of 64 here) ----
    const int lq = lane >> 4;
#pragma unroll
    for (int i = 0; i < 2; ++i) {
#pragma unroll
        for (int j = 0; j < 2; ++j) {
            const int gc = n0 + wc * 32 + j * 16 + lm;
#pragma unroll
            for (int rr = 0; rr < 4; ++rr) {
                const int gr = m0 + wr * 32 + i * 16 + lq * 4 + rr;
                if (gr < M) {
                    float v = acc[i][j][rr];
                    if (bias_mode == 1)      v += bias[gc];
                    else if (bias_mode == 2) v += bias[(size_t)gr * HH + gc];
                    else if (bias_mode == 3) v += bias[mapped_off(gr, kstep) + gc];
                    if (outf) {
                        size_t o = (outf_mode == 3 ? mapped_off(gr, kstep)
                                                   : (size_t)gr * HH) + gc;
                        outf[o] = v;
                    }
                    if (outhi) {
                        size_t o = (size_t)gr * HH + gc;
                        __bf16 h = (__bf16)v;
                        outhi[o] = h;
                        outlo[o] = (__bf16)(v - (float)h);
                    }
                }
            }
        }
    }
}

// ---------------------------------------------------------------------------
// Old generic kernel: kept for the U-power squarings (k-major B staging,
// padded 72-stride LDS => no conflicts) and as the wx fallback.
// ---------------------------------------------------------------------------
__global__ __launch_bounds__(256) void gemm_step(
    const void* Ahi_, const __bf16* Alo, int a_f32,
    const __bf16* Bthi, const __bf16* Btlo, int b_kmajor,
    int M, int K,
    const float* bias, int bias_mode, int kstep,
    float* outf, int outf_mode,
    __bf16* outhi, __bf16* outlo)
{
    __shared__ __align__(16) __bf16 As_hi[128][72];
    __shared__ __align__(16) __bf16 As_lo[128][72];
    __shared__ __align__(16) __bf16 Bs_hi[128][72];
    __shared__ __align__(16) __bf16 Bs_lo[128][72];

    const int tid  = threadIdx.x;
    const int lane = tid & 63;
    const int wid  = tid >> 6;
    const int wr = wid >> 1, wc = wid & 1;
    const int m0 = blockIdx.y * 128;
    const int n0 = blockIdx.x * 128;
    const bool has_a   = (Ahi_ != nullptr);
    const bool has_alo = (Alo  != nullptr);
    const bool has_blo = (Btlo != nullptr);

    floatx4 acc[4][4];
#pragma unroll
    for (int i = 0; i < 4; ++i)
#pragma unroll
        for (int j = 0; j < 4; ++j) {
            floatx4 z = {0.0f, 0.0f, 0.0f, 0.0f};
            acc[i][j] = z;
        }

    if (has_a) {
        const __bf16* Ahi = (const __bf16*)Ahi_;
        const float*  Af  = (const float*)Ahi_;
        for (int kt = 0; kt < K; kt += 64) {
#pragma unroll
            for (int it = 0; it < 4; ++it) {
                int chunk = tid + it * 256;
                int row = chunk >> 3;
                int col = (chunk & 7) << 3;
                if (a_f32) {
                    const float* src = Af + (size_t)(m0 + row) * K + kt + col;
                    float4 f0 = *(const float4*)src;
                    float4 f1 = *(const float4*)(src + 4);
                    __bf16* d = &As_hi[row][col];
                    d[0]=(__bf16)f0.x; d[1]=(__bf16)f0.y; d[2]=(__bf16)f0.z; d[3]=(__bf16)f0.w;
                    d[4]=(__bf16)f1.x; d[5]=(__bf16)f1.y; d[6]=(__bf16)f1.z; d[7]=(__bf16)f1.w;
                } else {
                    *(bf16_8*)&As_hi[row][col] =
                        *(const bf16_8*)(Ahi + (size_t)(m0 + row) * K + kt + col);
                    if (has_alo)
                        *(bf16_8*)&As_lo[row][col] =
                            *(const bf16_8*)(Alo + (size_t)(m0 + row) * K + kt + col);
                }
            }
            if (!b_kmajor) {
#pragma unroll
                for (int it = 0; it < 4; ++it) {
                    int chunk = tid + it * 256;
                    int row = chunk >> 3;
                    int col = (chunk & 7) << 3;
                    *(bf16_8*)&Bs_hi[row][col] =
                        *(const bf16_8*)(Bthi + (size_t)(n0 + row) * K + kt + col);
                    if (has_blo)
                        *(bf16_8*)&Bs_lo[row][col] =
                            *(const bf16_8*)(Btlo + (size_t)(n0 + row) * K + kt + col);
                }
            } else {
#pragma unroll
                for (int it = 0; it < 4; ++it) {
                    int chunk = tid + it * 256;
                    int krow = chunk >> 4;
                    int ncol = (chunk & 15) << 3;
                    bf16_8 v = *(const bf16_8*)(Bthi + (size_t)(kt + krow) * HH + n0 + ncol);
#pragma unroll
                    for (int e = 0; e < 8; ++e) Bs_hi[ncol + e][krow] = v[e];
                    if (has_blo) {
                        bf16_8 w = *(const bf16_8*)(Btlo + (size_t)(kt + krow) * HH + n0 + ncol);
#pragma unroll
                        for (int e = 0; e < 8; ++e) Bs_lo[ncol + e][krow] = w[e];
                    }
                }
            }
            __syncthreads();
#pragma unroll
            for (int ks = 0; ks < 64; ks += 32) {
                const int lm = lane & 15;
                const int kk = ks + (lane >> 4) * 8;
                bf16_8 ah[4], al[4], bh[4], bl[4];
#pragma unroll
                for (int i = 0; i < 4; ++i) {
                    ah[i] = *(const bf16_8*)&As_hi[wr * 64 + i * 16 + lm][kk];
                    if (has_alo) al[i] = *(const bf16_8*)&As_lo[wr * 64 + i * 16 + lm][kk];
                }
#pragma unroll
                for (int j = 0; j < 4; ++j) {
                    bh[j] = *(const bf16_8*)&Bs_hi[wc * 64 + j * 16 + lm][kk];
                    if (has_blo) bl[j] = *(const bf16_8*)&Bs_lo[wc * 64 + j * 16 + lm][kk];
                }
#pragma unroll
                for (int i = 0; i < 4; ++i)
#pragma unroll
                    for (int j = 0; j < 4; ++j) {
                        acc[i][j] = __builtin_amdgcn_mfma_f32_16x16x32_bf16(ah[i], bh[j], acc[i][j], 0, 0, 0);
                        if (has_alo)
                            acc[i][j] = __builtin_amdgcn_mfma_f32_16x16x32_bf16(al[i], bh[j], acc[i][j], 0, 0, 0);
                        if (has_blo)
                            acc[i][j] = __builtin_amdgcn_mfma_f32_16x16x32_bf16(ah[i], bl[j], acc[i][j], 0, 0, 0);
                    }
            }
            __syncthreads();
        }
    }

    const int lm = lane & 15, lq = lane >> 4;
#pragma unroll
    for (int i = 0; i < 4; ++i) {
#pragma unroll
        for (int j = 0; j < 4; ++j) {
            int gc = n0 + wc * 64 + j * 16 + lm;
#pragma unroll
            for (int rr = 0; rr < 4; ++rr) {
                int gr = m0 + wr * 64 + i * 16 + lq * 4 + rr;
                if (gr < M) {
                    float v = acc[i][j][rr];
                    if (bias_mode == 1)      v += bias[gc];
                    else if (bias_mode == 2) v += bias[(size_t)gr * HH + gc];
                    else if (bias_mode == 3) v += bias[mapped_off(gr, kstep) + gc];
                    if (outf) {
                        size_t o = (outf_mode == 3 ? mapped_off(gr, kstep)
                                                   : (size_t)gr * HH) + gc;
                        outf[o] = v;
                    }
                    if (outhi) {
                        size_t o = (size_t)gr * HH + gc;
                        __bf16 h = (__bf16)v;
                        outhi[o] = h;
                        outlo[o] = (__bf16)(v - (float)h);
                    }
                }
            }
        }
    }
}

__global__ void split_kernel(const float* src, __bf16* hi, __bf16* lo, int n) {
    int i = blockIdx.x * 256 + threadIdx.x;
    if (i < n) {
        float v = src[i];
        __bf16 h = (__bf16)v;
        hi[i] = h;
        lo[i] = (__bf16)(v - (float)h);
    }
}

__global__ void prep_wb(const float* W, const float* Ub, const float* bvec,
                        __bf16* Whi, float* biasv) {
    int i = blockIdx.x * 256 + threadIdx.x;
    if (i < 512 * 1024) {
        Whi[i] = (__bf16)W[i];
    } else if (i < 512 * 1024 + 1024) {
        int n = i - 512 * 1024;
        biasv[n] = Ub[n] + bvec[n];
    }
}

// Vectorized fp32 -> bf16 cast for x (8 elems/thread, exact grid coverage).
__global__ void cast_hi_kernel(const float* src, __bf16* hi) {
    size_t i = (size_t)blockIdx.x * 256 + threadIdx.x;
    float4 a = *(const float4*)(src + i * 8);
    float4 b = *(const float4*)(src + i * 8 + 4);
    bf16_8 v;
    v[0] = (__bf16)a.x; v[1] = (__bf16)a.y; v[2] = (__bf16)a.z; v[3] = (__bf16)a.w;
    v[4] = (__bf16)b.x; v[5] = (__bf16)b.y; v[6] = (__bf16)b.z; v[7] = (__bf16)b.w;
    *(bf16_8*)(hi + i * 8) = v;
}

// Build phase-3 initial state: rows of chunk c get e_{c-1} (chunk 0 gets zeros).
__global__ void p3init_kernel(const __bf16* Hhi, const __bf16* Hlo,
                              __bf16* S0hi, __bf16* S0lo) {
    size_t i = (size_t)blockIdx.x * 256 + threadIdx.x;  // over 4096*1024
    int col = (int)(i & 1023);
    int r = (int)(i >> 10);
    int c = r >> 6;
    int b = r & 63;
    if (c == 0) {
        S0hi[i] = (__bf16)0.0f;
        S0lo[i] = (__bf16)0.0f;
    } else {
        size_t src = ((size_t)((c - 1) * 64 + b) << 10) + col;
        S0hi[i] = Hhi[src];
        S0lo[i] = Hlo[src];
    }
}

extern "C" void kernel_launch(void* const* d_in, const int* in_sizes, int n_in,
                              void* d_out_, int out_size, void* d_ws, size_t ws_size,
                              hipStream_t stream) {
    const float* x   = (const float*)d_in[0];  // [64,2048,512]
    const float* W   = (const float*)d_in[1];  // [1024,512]
    const float* Uw  = (const float*)d_in[2];  // [1024,1024]
    const float* Ub  = (const float*)d_in[3];  // [1024]
    const float* bvec= (const float*)d_in[4];  // [1024] (zeros)
    float* out = (float*)d_out_;               // [64,2048,1024]

    char* p = (char*)d_ws;
    size_t need = 0;
    auto alloc = [&](size_t bytes) { char* r = p; p += bytes; need += bytes; return r; };
    __bf16* Uhi  = (__bf16*)alloc(2097152);
    __bf16* Ulo  = (__bf16*)alloc(2097152);
    __bf16* Whi  = (__bf16*)alloc(1048576);
    float*  biasv= (float*) alloc(4096);
    __bf16* Phi  = (__bf16*)alloc(2097152);
    __bf16* Plo  = (__bf16*)alloc(2097152);
    __bf16* Qhi  = (__bf16*)alloc(2097152);
    __bf16* Qlo  = (__bf16*)alloc(2097152);
    __bf16* SAhi = (__bf16*)alloc(8388608);
    __bf16* SAlo = (__bf16*)alloc(8388608);
    __bf16* SBhi = (__bf16*)alloc(8388608);
    __bf16* SBlo = (__bf16*)alloc(8388608);
    float*  Sf   = (float*) alloc(16777216);
    __bf16* Hhi  = (__bf16*)alloc(8388608);
    __bf16* Hlo  = (__bf16*)alloc(8388608);
    size_t base_need = need;
    __bf16* xhi  = (__bf16*)alloc(134217728);     // optional bf16 copy of x
    const bool use_xhi = (ws_size >= need);
    if (ws_size < base_need) return;  // workspace too small: fail loudly

    // prep: split Uw, quantize W, bias vector
    split_kernel<<<4096, 256, 0, stream>>>(Uw, Uhi, Ulo, 1024 * 1024);
    prep_wb<<<2052, 256, 0, stream>>>(W, Ub, bvec, Whi, biasv);

    // wx = x*W^T + Ub + b -> d_out (fp32), M=131072 rows == (b,t) layout
    if (use_xhi) {
        cast_hi_kernel<<<32768, 256, 0, stream>>>(x, xhi);
        step_gemm<<<dim3(8, 2048), 512, 0, stream>>>(
            xhi, nullptr, Whi, nullptr, 131072, 512,
            biasv, 1, 0, out, 2, nullptr, nullptr);
    } else {
        gemm_step<<<dim3(8, 1024), 256, 0, stream>>>(
            (const void*)x, nullptr, 1, Whi, nullptr, 0,
            131072, 512, biasv, 1, 0, out, 2, nullptr, nullptr);
    }

    // Uw^32 by repeated squaring (split-3, k-major B = same matrix)
    gemm_step<<<dim3(8, 8), 256, 0, stream>>>((const void*)Uhi, Ulo, 0, Uhi, Ulo, 1,
        1024, 1024, nullptr, 0, 0, nullptr, 0, Qhi, Qlo);              // U^2
    gemm_step<<<dim3(8, 8), 256, 0, stream>>>((const void*)Qhi, Qlo, 0, Qhi, Qlo, 1,
        1024, 1024, nullptr, 0, 0, nullptr, 0, Phi, Plo);              // U^4
    gemm_step<<<dim3(8, 8), 256, 0, stream>>>((const void*)Phi, Plo, 0, Phi, Plo, 1,
        1024, 1024, nullptr, 0, 0, nullptr, 0, Qhi, Qlo);              // U^8
    gemm_step<<<dim3(8, 8), 256, 0, stream>>>((const void*)Qhi, Qlo, 0, Qhi, Qlo, 1,
        1024, 1024, nullptr, 0, 0, nullptr, 0, Phi, Plo);              // U^16
    gemm_step<<<dim3(8, 8), 256, 0, stream>>>((const void*)Phi, Plo, 0, Phi, Plo, 1,
        1024, 1024, nullptr, 0, 0, nullptr, 0, Qhi, Qlo);              // U^32 -> Q

    // phase 1: local scans (zero init), 64 chunks x 64 batch = 4096 rows.
    // Sf only needs the chunk-end value -> write it on the last step only.
    // hi/lo of the last step are dead (p3init overwrites) -> skip them.
    __bf16 *pin_hi = SAhi, *pin_lo = SAlo, *pout_hi = SBhi, *pout_lo = SBlo;
    for (int k = 0; k < LSTEPS; ++k) {
        const __bf16* ah = (k == 0) ? nullptr : pin_hi;
        const __bf16* al = (k == 0) ? nullptr : pin_lo;
        float* of = (k == LSTEPS - 1) ? Sf : nullptr;
        __bf16* oh = (k == LSTEPS - 1) ? nullptr : pout_hi;
        __bf16* ol = (k == LSTEPS - 1) ? nullptr : pout_lo;
        step_gemm<<<dim3(8, 64), 512, 0, stream>>>(
            ah, al, Uhi, Ulo, 4096, 1024, out, 3, k, of, 2, oh, ol);
        __bf16* t;
        t = pin_hi; pin_hi = pout_hi; pout_hi = t;
        t = pin_lo; pin_lo = pout_lo; pout_lo = t;
    }

    // phase 2: chunk-boundary propagation e_c = U^32 e_{c-1} + local_end_c
    for (int c = 0; c < CC; ++c) {
        const __bf16* ah = (c == 0) ? nullptr : Hhi + (size_t)(c - 1) * 65536;
        const __bf16* al = (c == 0) ? nullptr : Hlo + (size_t)(c - 1) * 65536;
        step_gemm<<<dim3(8, 1), 512, 0, stream>>>(
            ah, al, Qhi, Qlo, 64, 1024,
            Sf + (size_t)c * 65536, 2, 0, nullptr, 0,
            Hhi + (size_t)c * 65536, Hlo + (size_t)c * 65536);
    }

    // phase-3 init: chunk c rows <- e_{c-1}
    p3init_kernel<<<16384, 256, 0, stream>>>(Hhi, Hlo, SAhi, SAlo);

    // phase 3: rescan with true inits, writing d_out in place.
    // hi/lo of the last step are never read -> skip them.
    pin_hi = SAhi; pin_lo = SAlo; pout_hi = SBhi; pout_lo = SBlo;
    for (int k = 0; k < LSTEPS; ++k) {
        __bf16* oh = (k == LSTEPS - 1) ? nullptr : pout_hi;
        __bf16* ol = (k == LSTEPS - 1) ? nullptr : pout_lo;
        step_gemm<<<dim3(8, 64), 512, 0, stream>>>(
            pin_hi, pin_lo, Uhi, Ulo, 4096, 1024, out, 3, k, out, 3, oh, ol);
        __bf16* t;
        t = pin_hi; pin_hi = pout_hi; pout_hi = t;
        t = pin_lo; pin_lo = pout_lo; pout_lo = t;
    }
}